// Round 1
// baseline (389.958 us; speedup 1.0000x reference)
//
#include <hip/hip_runtime.h>

// B=4 T=2048 C=1024 H=16 D=64  N=B*T=8192
// bf16 storage as unsigned short; MFMA frags as short8 (guide §3 verified typedef)

typedef __attribute__((ext_vector_type(8))) short short8;
typedef __attribute__((ext_vector_type(4))) float f32x4;

__device__ __forceinline__ unsigned short f2b(float f) {
  union { float f; unsigned int i; } x; x.f = f;
  return (unsigned short)((x.i + 0x7FFFu + ((x.i >> 16) & 1u)) >> 16);
}

__device__ __forceinline__ void glds16(const void* g, void* l) {
  __builtin_amdgcn_global_load_lds((const __attribute__((address_space(1))) unsigned int*)g,
                                   (__attribute__((address_space(3))) unsigned int*)l,
                                   16, 0, 0);
}

__device__ __forceinline__ f32x4 mfma16(short8 a, short8 b, f32x4 c) {
  return __builtin_amdgcn_mfma_f32_16x16x32_bf16(a, b, c, 0, 0, 0);
}

// ---------------- cast x: f32 -> bf16, 8 elems/thread ----------------
__global__ __launch_bounds__(256) void cast_x_kernel(const float* __restrict__ x,
                                                     unsigned short* __restrict__ xb) {
  const long i = ((long)blockIdx.x * 256 + threadIdx.x) * 8;
  const float4 a = *(const float4*)(x + i);
  const float4 b = *(const float4*)(x + i + 4);
  unsigned short o[8] = {f2b(a.x), f2b(a.y), f2b(a.z), f2b(a.w),
                         f2b(b.x), f2b(b.y), f2b(b.z), f2b(b.w)};
  *(short8*)(xb + i) = *(const short8*)o;
}

// ---------------- transpose+cast weights: dst[n][k] = W[k][n] ----------------
__global__ __launch_bounds__(256) void transpose_cast_w(
    const float* __restrict__ W0, const float* __restrict__ W1,
    const float* __restrict__ W2, const float* __restrict__ W3,
    unsigned short* __restrict__ Wt, unsigned short* __restrict__ Wot) {
  const int z = blockIdx.z;
  const float* __restrict__ W = (z == 0) ? W0 : (z == 1) ? W1 : (z == 2) ? W2 : W3;
  unsigned short* __restrict__ dst = (z < 3) ? (Wt + (size_t)z * 1024 * 1024) : Wot;
  __shared__ float tile[32][33];
  const int tx = threadIdx.x, ty = threadIdx.y;
  const int bx = blockIdx.x * 32, by = blockIdx.y * 32;
#pragma unroll
  for (int i = 0; i < 4; ++i)
    tile[ty + 8 * i][tx] = W[(size_t)(by + ty + 8 * i) * 1024 + bx + tx];
  __syncthreads();
#pragma unroll
  for (int i = 0; i < 4; ++i)
    dst[(size_t)(bx + ty + 8 * i) * 1024 + by + tx] = f2b(tile[tx][ty + 8 * i]);
}

// ---------------- QKV GEMM (M=8192,N=3072,K=1024) + fused RoPE/RMS epilogue ----------------
// A: xb [8192][1024] bf16 ; Bt: Wt [3072][1024] bf16 (W^T, q|k|v stacked)
// out: Qr/Kr/Vr bf16 in [B][H][T][D]
__global__ __launch_bounds__(256) void gemm_qkv(
    const unsigned short* __restrict__ A, const unsigned short* __restrict__ Bt,
    unsigned short* __restrict__ Qr, unsigned short* __restrict__ Kr,
    unsigned short* __restrict__ Vr,
    const float* __restrict__ cosp, const float* __restrict__ sinp) {
  __shared__ unsigned short As[128 * 32];
  __shared__ unsigned short Bs[128 * 32];
  const int tid = threadIdx.x;
  const int wave = tid >> 6, lane = tid & 63;
  const int ln = lane & 15, grp = lane >> 4;
  const int wr = wave >> 1, wc = wave & 1;
  const int row0 = blockIdx.x * 128, col0 = blockIdx.y * 128;

  f32x4 acc[4][4];
  const f32x4 z4 = {0.f, 0.f, 0.f, 0.f};
#pragma unroll
  for (int m = 0; m < 4; ++m)
#pragma unroll
    for (int n = 0; n < 4; ++n) acc[m][n] = z4;

  for (int k0 = 0; k0 < 1024; k0 += 32) {
    __syncthreads();
#pragma unroll
    for (int p = 0; p < 2; ++p) {
      const int lin = p * 256 + tid;       // 16B chunk index
      const int r = lin >> 2;              // 0..127 tile row
      const int c8 = (lin & 3) * 8;        // elem col
      glds16(A + (long)(row0 + r) * 1024 + k0 + c8, (char*)As + p * 4096 + wave * 1024);
      glds16(Bt + (long)(col0 + r) * 1024 + k0 + c8, (char*)Bs + p * 4096 + wave * 1024);
    }
    __syncthreads();
    short8 af[4], bfv[4];
#pragma unroll
    for (int m = 0; m < 4; ++m)
      af[m] = *(const short8*)&As[(wr * 64 + m * 16 + ln) * 32 + grp * 8];
#pragma unroll
    for (int n = 0; n < 4; ++n)
      bfv[n] = *(const short8*)&Bs[(wc * 64 + n * 16 + ln) * 32 + grp * 8];
#pragma unroll
    for (int m = 0; m < 4; ++m)
#pragma unroll
      for (int n = 0; n < 4; ++n)
        acc[m][n] = mfma16(af[m], bfv[n], acc[m][n]);
  }

  // epilogue: each wave's 64-col block == one head of one of q/k/v
  const int colbase = col0 + wc * 64;
  const int z = colbase >> 10;
  const int h = (colbase & 1023) >> 6;
  unsigned short* __restrict__ dst = (z == 0) ? Qr : (z == 1) ? Kr : Vr;

  if (z < 2) {  // RoPE + RMS-norm for Q,K
#pragma unroll
    for (int m = 0; m < 4; ++m) {
#pragma unroll
      for (int reg = 0; reg < 4; ++reg) {
        const int row = row0 + wr * 64 + m * 16 + grp * 4 + reg;
        const int t = row & 2047, b = row >> 11;
        const float u0 = acc[m][0][reg], u1 = acc[m][1][reg];
        const float u2 = acc[m][2][reg], u3 = acc[m][3][reg];
        const float c0 = cosp[t * 32 + ln],      s0 = sinp[t * 32 + ln];
        const float c1 = cosp[t * 32 + 16 + ln], s1 = sinp[t * 32 + 16 + ln];
        const float r0 =  u0 * c0 + u2 * s0;
        const float r1 =  u1 * c1 + u3 * s1;
        const float r2 = -u0 * s0 + u2 * c0;
        const float r3 = -u1 * s1 + u3 * c1;
        float ss = r0 * r0 + r1 * r1 + r2 * r2 + r3 * r3;
        ss += __shfl_xor(ss, 1); ss += __shfl_xor(ss, 2);
        ss += __shfl_xor(ss, 4); ss += __shfl_xor(ss, 8);
        const float inv = rsqrtf(ss * (1.0f / 64.0f) + 1.1920929e-07f);
        const long base = (((long)(b * 16 + h)) * 2048 + t) * 64;
        dst[base + ln]      = f2b(r0 * inv);
        dst[base + 16 + ln] = f2b(r1 * inv);
        dst[base + 32 + ln] = f2b(r2 * inv);
        dst[base + 48 + ln] = f2b(r3 * inv);
      }
    }
  } else {  // plain relayout for V
#pragma unroll
    for (int m = 0; m < 4; ++m) {
#pragma unroll
      for (int reg = 0; reg < 4; ++reg) {
        const int row = row0 + wr * 64 + m * 16 + grp * 4 + reg;
        const int t = row & 2047, b = row >> 11;
        const long base = (((long)(b * 16 + h)) * 2048 + t) * 64;
#pragma unroll
        for (int n = 0; n < 4; ++n)
          dst[base + n * 16 + ln] = f2b(acc[m][n][reg]);
      }
    }
  }
}

// ---------------- causal flash attention ----------------
// Q/K/V: bf16 [B*H][T][64]; Y: bf16 [B][T][H][64]
__global__ __launch_bounds__(256) void attn_kernel(
    const unsigned short* __restrict__ Q, const unsigned short* __restrict__ K,
    const unsigned short* __restrict__ V, unsigned short* __restrict__ Y) {
  __shared__ unsigned short Kt[64 * 64];      // [kv][d], XOR-swizzled rows
  __shared__ unsigned short Vt[64 * 72];      // [d][kv], stride 72
  __shared__ unsigned short Pl[4 * 16 * 64];  // per-wave P tile, swizzled
  const int bh = blockIdx.y, qblk = blockIdx.x;
  const int tid = threadIdx.x;
  const int wave = tid >> 6, lane = tid & 63;
  const int ln = lane & 15, grp = lane >> 4;
  const long bhT = (long)bh * 2048;
  const int qbase = qblk * 64;

  // Q fragments (A operand), rows = qbase + wave*16 + ln
  const unsigned short* qp = Q + (bhT + qbase + wave * 16 + ln) * 64 + grp * 8;
  short8 aq[2];
  aq[0] = *(const short8*)qp;
  aq[1] = *(const short8*)(qp + 32);

  f32x4 accO[4];
  const f32x4 z4 = {0.f, 0.f, 0.f, 0.f};
#pragma unroll
  for (int dt = 0; dt < 4; ++dt) accO[dt] = z4;
  float m_r[4] = {-INFINITY, -INFINITY, -INFINITY, -INFINITY};
  float l_r[4] = {0.f, 0.f, 0.f, 0.f};
  unsigned short* pw = Pl + wave * 1024;

  for (int j = 0; j <= qblk; ++j) {
    const long kvoff = bhT + j * 64;
    __syncthreads();
    // stage K with XOR swizzle via pre-swizzled global source (rule #21)
#pragma unroll
    for (int p = 0; p < 2; ++p) {
      const int lin = (p * 256 + tid) * 16;  // byte in Kt
      const int row = lin >> 7;
      const int cb = (lin & 127) ^ ((row & 7) << 4);
      glds16(K + (kvoff + row) * 64 + (cb >> 1), (char*)Kt + p * 4096 + wave * 1024);
    }
    // stage V transposed: Vt[d][kv]
    {
      const int kv = tid >> 2;
      const int d0 = (tid & 3) * 16;
      const unsigned short* vs = V + (kvoff + kv) * 64 + d0;
      short8 v0 = *(const short8*)vs;
      short8 v1 = *(const short8*)(vs + 8);
#pragma unroll
      for (int jj = 0; jj < 8; ++jj) {
        Vt[(d0 + jj) * 72 + kv]     = (unsigned short)v0[jj];
        Vt[(d0 + 8 + jj) * 72 + kv] = (unsigned short)v1[jj];
      }
    }
    __syncthreads();

    // S = Q K^T  (per wave: 16 q rows x 64 kv cols)
    f32x4 sacc[4];
#pragma unroll
    for (int ct = 0; ct < 4; ++ct) sacc[ct] = z4;
#pragma unroll
    for (int ct = 0; ct < 4; ++ct) {
      const int row = ct * 16 + ln;
      const int sw = (row & 7) << 4;
#pragma unroll
      for (int c = 0; c < 2; ++c) {
        const int byte = row * 128 + ((grp * 16 + c * 64) ^ sw);
        short8 bk = *(const short8*)((const char*)Kt + byte);
        sacc[ct] = mfma16(aq[c], bk, sacc[ct]);
      }
    }

    // online softmax (rows: grp*4+reg, cols across 16 lanes x 4 ct)
#pragma unroll
    for (int reg = 0; reg < 4; ++reg) {
      const int qg = qbase + wave * 16 + grp * 4 + reg;
      float sv[4];
      float mx = -INFINITY;
#pragma unroll
      for (int ct = 0; ct < 4; ++ct) {
        float s = sacc[ct][reg] * 0.125f;
        const int kvc = j * 64 + ct * 16 + ln;
        if (kvc > qg) s = -INFINITY;
        sv[ct] = s;
        mx = fmaxf(mx, s);
      }
      mx = fmaxf(mx, __shfl_xor(mx, 1)); mx = fmaxf(mx, __shfl_xor(mx, 2));
      mx = fmaxf(mx, __shfl_xor(mx, 4)); mx = fmaxf(mx, __shfl_xor(mx, 8));
      const float mnew = fmaxf(m_r[reg], mx);
      const float alpha = __expf(m_r[reg] - mnew);
      m_r[reg] = mnew;
      float rs = 0.f;
#pragma unroll
      for (int ct = 0; ct < 4; ++ct) {
        const float p = __expf(sv[ct] - mnew);
        sacc[ct][reg] = p;
        rs += p;
      }
      rs += __shfl_xor(rs, 1); rs += __shfl_xor(rs, 2);
      rs += __shfl_xor(rs, 4); rs += __shfl_xor(rs, 8);
      l_r[reg] = l_r[reg] * alpha + rs;
#pragma unroll
      for (int dt = 0; dt < 4; ++dt) accO[dt][reg] *= alpha;
    }

    // P -> LDS (wave-private, swizzled), then A-fragments for PV
#pragma unroll
    for (int reg = 0; reg < 4; ++reg) {
      const int q = grp * 4 + reg;
      const int sw = (q & 7) << 4;
#pragma unroll
      for (int ct = 0; ct < 4; ++ct) {
        const int byte = q * 128 + ((ct * 32 + ln * 2) ^ sw);
        *(unsigned short*)((char*)pw + byte) = f2b(sacc[ct][reg]);
      }
    }
    short8 pa[2];
    {
      const int sw = (ln & 7) << 4;
      pa[0] = *(const short8*)((const char*)pw + ln * 128 + ((grp * 16) ^ sw));
      pa[1] = *(const short8*)((const char*)pw + ln * 128 + ((grp * 16 + 64) ^ sw));
    }
#pragma unroll
    for (int dt = 0; dt < 4; ++dt) {
#pragma unroll
      for (int c = 0; c < 2; ++c) {
        short8 bv = *(const short8*)&Vt[(dt * 16 + ln) * 72 + c * 32 + grp * 8];
        accO[dt] = mfma16(pa[c], bv, accO[dt]);
      }
    }
  }

  // epilogue: Y[b][t][h][d]
  const int b = bh >> 4, h = bh & 15;
#pragma unroll
  for (int reg = 0; reg < 4; ++reg) {
    const float inv = 1.0f / l_r[reg];
    const int t = qbase + wave * 16 + grp * 4 + reg;
    const long base = (((long)(b * 2048 + t)) * 16 + h) * 64;
#pragma unroll
    for (int dt = 0; dt < 4; ++dt)
      Y[base + dt * 16 + ln] = f2b(accO[dt][reg] * inv);
  }
}

// ---------------- output GEMM (M=8192,N=1024,K=1024), f32 out ----------------
__global__ __launch_bounds__(256) void gemm_out(
    const unsigned short* __restrict__ A, const unsigned short* __restrict__ Bt,
    float* __restrict__ C) {
  __shared__ unsigned short As[128 * 32];
  __shared__ unsigned short Bs[128 * 32];
  const int tid = threadIdx.x;
  const int wave = tid >> 6, lane = tid & 63;
  const int ln = lane & 15, grp = lane >> 4;
  const int wr = wave >> 1, wc = wave & 1;
  const int row0 = blockIdx.x * 128, col0 = blockIdx.y * 128;

  f32x4 acc[4][4];
  const f32x4 z4 = {0.f, 0.f, 0.f, 0.f};
#pragma unroll
  for (int m = 0; m < 4; ++m)
#pragma unroll
    for (int n = 0; n < 4; ++n) acc[m][n] = z4;

  for (int k0 = 0; k0 < 1024; k0 += 32) {
    __syncthreads();
#pragma unroll
    for (int p = 0; p < 2; ++p) {
      const int lin = p * 256 + tid;
      const int r = lin >> 2;
      const int c8 = (lin & 3) * 8;
      glds16(A + (long)(row0 + r) * 1024 + k0 + c8, (char*)As + p * 4096 + wave * 1024);
      glds16(Bt + (long)(col0 + r) * 1024 + k0 + c8, (char*)Bs + p * 4096 + wave * 1024);
    }
    __syncthreads();
    short8 af[4], bfv[4];
#pragma unroll
    for (int m = 0; m < 4; ++m)
      af[m] = *(const short8*)&As[(wr * 64 + m * 16 + ln) * 32 + grp * 8];
#pragma unroll
    for (int n = 0; n < 4; ++n)
      bfv[n] = *(const short8*)&Bs[(wc * 64 + n * 16 + ln) * 32 + grp * 8];
#pragma unroll
    for (int m = 0; m < 4; ++m)
#pragma unroll
      for (int n = 0; n < 4; ++n)
        acc[m][n] = mfma16(af[m], bfv[n], acc[m][n]);
  }

#pragma unroll
  for (int m = 0; m < 4; ++m)
#pragma unroll
    for (int reg = 0; reg < 4; ++reg) {
      const int row = row0 + wr * 64 + m * 16 + grp * 4 + reg;
#pragma unroll
      for (int n = 0; n < 4; ++n)
        C[(long)row * 1024 + col0 + wc * 64 + n * 16 + ln] = acc[m][n][reg];
    }
}

extern "C" void kernel_launch(void* const* d_in, const int* in_sizes, int n_in,
                              void* d_out, int out_size, void* d_ws, size_t ws_size,
                              hipStream_t stream) {
  (void)in_sizes; (void)n_in; (void)out_size; (void)ws_size;
  const float* x    = (const float*)d_in[0];
  const float* cosp = (const float*)d_in[1];
  const float* sinp = (const float*)d_in[2];
  const float* Wq   = (const float*)d_in[3];
  const float* Wk   = (const float*)d_in[4];
  const float* Wv   = (const float*)d_in[5];
  const float* Wo   = (const float*)d_in[6];
  float* out = (float*)d_out;

  // workspace layout (bf16 elems): xb 8M | Wt 3M | Wot 1M | Qr 8M | Kr 8M | Vr 8M  = 72 MB
  unsigned short* xb  = (unsigned short*)d_ws;
  unsigned short* Wt  = xb  + (size_t)8192 * 1024;
  unsigned short* Wot = Wt  + (size_t)3 * 1024 * 1024;
  unsigned short* Qr  = Wot + (size_t)1024 * 1024;
  unsigned short* Kr  = Qr  + (size_t)8192 * 1024;
  unsigned short* Vr  = Kr  + (size_t)8192 * 1024;
  unsigned short* Yb  = xb;  // xb dead after gemm_qkv; reuse for attention output

  cast_x_kernel<<<4096, 256, 0, stream>>>(x, xb);
  transpose_cast_w<<<dim3(32, 32, 4), dim3(32, 8), 0, stream>>>(Wq, Wk, Wv, Wo, Wt, Wot);
  gemm_qkv<<<dim3(64, 24), 256, 0, stream>>>(xb, Wt, Qr, Kr, Vr, cosp, sinp);
  attn_kernel<<<dim3(32, 64), 256, 0, stream>>>(Qr, Kr, Vr, Yb);
  gemm_out<<<dim3(64, 8), 256, 0, stream>>>(Yb, Wot, out);
}

// Round 2
// 237.811 us; speedup vs baseline: 1.6398x; 1.6398x over previous
//
#include <hip/hip_runtime.h>

// B=4 T=2048 C=1024 H=16 D=64  N=B*T=8192

typedef __attribute__((ext_vector_type(8))) short short8;
typedef __attribute__((ext_vector_type(4))) short short4v;
typedef __attribute__((ext_vector_type(4))) float f32x4;

__device__ __forceinline__ unsigned short f2b(float f) {
  union { float f; unsigned int i; } x; x.f = f;
  return (unsigned short)((x.i + 0x7FFFu + ((x.i >> 16) & 1u)) >> 16);
}

__device__ __forceinline__ void glds16(const void* g, void* l) {
  __builtin_amdgcn_global_load_lds((const __attribute__((address_space(1))) unsigned int*)g,
                                   (__attribute__((address_space(3))) unsigned int*)l,
                                   16, 0, 0);
}

__device__ __forceinline__ f32x4 mfma16(short8 a, short8 b, f32x4 c) {
  return __builtin_amdgcn_mfma_f32_16x16x32_bf16(a, b, c, 0, 0, 0);
}

// ---------------- cast x: f32 -> bf16, 8 elems/thread ----------------
__global__ __launch_bounds__(256) void cast_x_kernel(const float* __restrict__ x,
                                                     unsigned short* __restrict__ xb) {
  const long i = ((long)blockIdx.x * 256 + threadIdx.x) * 8;
  const float4 a = *(const float4*)(x + i);
  const float4 b = *(const float4*)(x + i + 4);
  unsigned short o[8] = {f2b(a.x), f2b(a.y), f2b(a.z), f2b(a.w),
                         f2b(b.x), f2b(b.y), f2b(b.z), f2b(b.w)};
  *(short8*)(xb + i) = *(const short8*)o;
}

// ---------------- transpose+cast weights: dst[n][k] = W[k][n] ----------------
__global__ __launch_bounds__(256) void transpose_cast_w(
    const float* __restrict__ W0, const float* __restrict__ W1,
    const float* __restrict__ W2, const float* __restrict__ W3,
    unsigned short* __restrict__ Wt, unsigned short* __restrict__ Wot) {
  const int z = blockIdx.z;
  const float* __restrict__ W = (z == 0) ? W0 : (z == 1) ? W1 : (z == 2) ? W2 : W3;
  unsigned short* __restrict__ dst = (z < 3) ? (Wt + (size_t)z * 1024 * 1024) : Wot;
  __shared__ float tile[32][33];
  const int tx = threadIdx.x, ty = threadIdx.y;
  const int bx = blockIdx.x * 32, by = blockIdx.y * 32;
#pragma unroll
  for (int i = 0; i < 4; ++i)
    tile[ty + 8 * i][tx] = W[(size_t)(by + ty + 8 * i) * 1024 + bx + tx];
  __syncthreads();
#pragma unroll
  for (int i = 0; i < 4; ++i)
    dst[(size_t)(bx + ty + 8 * i) * 1024 + by + tx] = f2b(tile[tx][ty + 8 * i]);
}

// ---------------- QKV GEMM (M=8192,N=3072,K=1024) + fused RoPE/RMS epilogue ----------------
// Q is additionally pre-scaled by 1/sqrt(D)=0.125 (exact power-of-2).
__global__ __launch_bounds__(256) void gemm_qkv(
    const unsigned short* __restrict__ A, const unsigned short* __restrict__ Bt,
    unsigned short* __restrict__ Qr, unsigned short* __restrict__ Kr,
    unsigned short* __restrict__ Vr,
    const float* __restrict__ cosp, const float* __restrict__ sinp) {
  __shared__ unsigned short As[128 * 32];
  __shared__ unsigned short Bs[128 * 32];
  const int tid = threadIdx.x;
  const int wave = tid >> 6, lane = tid & 63;
  const int ln = lane & 15, grp = lane >> 4;
  const int wr = wave >> 1, wc = wave & 1;
  const int row0 = blockIdx.x * 128, col0 = blockIdx.y * 128;

  f32x4 acc[4][4];
  const f32x4 z4 = {0.f, 0.f, 0.f, 0.f};
#pragma unroll
  for (int m = 0; m < 4; ++m)
#pragma unroll
    for (int n = 0; n < 4; ++n) acc[m][n] = z4;

  for (int k0 = 0; k0 < 1024; k0 += 32) {
    __syncthreads();
#pragma unroll
    for (int p = 0; p < 2; ++p) {
      const int lin = p * 256 + tid;
      const int r = lin >> 2;
      const int c8 = (lin & 3) * 8;
      glds16(A + (long)(row0 + r) * 1024 + k0 + c8, (char*)As + p * 4096 + wave * 1024);
      glds16(Bt + (long)(col0 + r) * 1024 + k0 + c8, (char*)Bs + p * 4096 + wave * 1024);
    }
    __syncthreads();
    short8 af[4], bfv[4];
#pragma unroll
    for (int m = 0; m < 4; ++m)
      af[m] = *(const short8*)&As[(wr * 64 + m * 16 + ln) * 32 + grp * 8];
#pragma unroll
    for (int n = 0; n < 4; ++n)
      bfv[n] = *(const short8*)&Bs[(wc * 64 + n * 16 + ln) * 32 + grp * 8];
#pragma unroll
    for (int m = 0; m < 4; ++m)
#pragma unroll
      for (int n = 0; n < 4; ++n)
        acc[m][n] = mfma16(af[m], bfv[n], acc[m][n]);
  }

  const int colbase = col0 + wc * 64;
  const int z = colbase >> 10;
  const int h = (colbase & 1023) >> 6;
  unsigned short* __restrict__ dst = (z == 0) ? Qr : (z == 1) ? Kr : Vr;

  if (z < 2) {  // RoPE + RMS-norm for Q,K (Q pre-scaled by 0.125)
    const float qs = (z == 0) ? 0.125f : 1.0f;
#pragma unroll
    for (int m = 0; m < 4; ++m) {
#pragma unroll
      for (int reg = 0; reg < 4; ++reg) {
        const int row = row0 + wr * 64 + m * 16 + grp * 4 + reg;
        const int t = row & 2047, b = row >> 11;
        const float u0 = acc[m][0][reg], u1 = acc[m][1][reg];
        const float u2 = acc[m][2][reg], u3 = acc[m][3][reg];
        const float c0 = cosp[t * 32 + ln],      s0 = sinp[t * 32 + ln];
        const float c1 = cosp[t * 32 + 16 + ln], s1 = sinp[t * 32 + 16 + ln];
        const float r0 =  u0 * c0 + u2 * s0;
        const float r1 =  u1 * c1 + u3 * s1;
        const float r2 = -u0 * s0 + u2 * c0;
        const float r3 = -u1 * s1 + u3 * c1;
        float ss = r0 * r0 + r1 * r1 + r2 * r2 + r3 * r3;
        ss += __shfl_xor(ss, 1); ss += __shfl_xor(ss, 2);
        ss += __shfl_xor(ss, 4); ss += __shfl_xor(ss, 8);
        const float inv = rsqrtf(ss * (1.0f / 64.0f) + 1.1920929e-07f) * qs;
        const long base = (((long)(b * 16 + h)) * 2048 + t) * 64;
        dst[base + ln]      = f2b(r0 * inv);
        dst[base + 16 + ln] = f2b(r1 * inv);
        dst[base + 32 + ln] = f2b(r2 * inv);
        dst[base + 48 + ln] = f2b(r3 * inv);
      }
    }
  } else {  // plain relayout for V
#pragma unroll
    for (int m = 0; m < 4; ++m) {
#pragma unroll
      for (int reg = 0; reg < 4; ++reg) {
        const int row = row0 + wr * 64 + m * 16 + grp * 4 + reg;
        const int t = row & 2047, b = row >> 11;
        const long base = (((long)(b * 16 + h)) * 2048 + t) * 64;
#pragma unroll
        for (int n = 0; n < 4; ++n)
          dst[base + n * 16 + ln] = f2b(acc[m][n][reg]);
      }
    }
  }
}

// ---------------- causal flash attention (swapped-operand, tr-read V) ----------------
// Q/K/V: bf16 [B*H][T][64]; Y: bf16 [B][T][H][64]
// Per block: 128 q rows (4 waves x 32), KVBLK=64, double-buffered K/V staging.
__global__ __launch_bounds__(256) void attn_kernel(
    const unsigned short* __restrict__ Q, const unsigned short* __restrict__ K,
    const unsigned short* __restrict__ V, unsigned short* __restrict__ Y) {
  // per buffer (u16): K [64 rows][64] XOR-swizzled (4096) | V subtiled [d_t4][kv_t16][4][16] (4096)
  __shared__ unsigned short lds[2 * 8192];
  const int tid = threadIdx.x;
  const int wave = tid >> 6, lane = tid & 63;
  const int ln = lane & 15, grp = lane >> 4;

  // XCD swizzle: 1024 blocks; XCD x serves bh = x*8..x*8+7 (K/V footprint 4MB = one L2)
  const int linb = blockIdx.x;
  const int xcd = linb & 7, slot = linb >> 3;
  const int bh = xcd * 8 + (slot >> 4);
  const int bx = slot & 15;

  const long bhT = (long)bh * 2048;
  const int q0 = bx * 128;
  const int qw = q0 + wave * 32;
  const int jmax = 2 * bx + 1;
  const int jdiag = 2 * bx;

  // Q b-frags (B operand of S^T = K*Q^T): lane holds Q[qrow=ln of tile][d=grp*8+j+32c]
  short8 qf[2][2];
#pragma unroll
  for (int nt = 0; nt < 2; ++nt)
#pragma unroll
    for (int c = 0; c < 2; ++c)
      qf[nt][c] = *(const short8*)(Q + (bhT + qw + nt * 16 + ln) * 64 + c * 32 + grp * 8);

  f32x4 accO[4][2];
  const f32x4 z4 = {0.f, 0.f, 0.f, 0.f};
#pragma unroll
  for (int dt = 0; dt < 4; ++dt) { accO[dt][0] = z4; accO[dt][1] = z4; }
  float m_run[2] = {-INFINITY, -INFINITY};
  float l_run[2] = {0.f, 0.f};

  auto* lds3 = (__attribute__((address_space(3))) unsigned short*)lds;

  // stage K (row-XOR-swizzled) + V (subtiled linear) via global_load_lds
  auto stage = [&](int j, int buf) {
    const long kvoff = bhT + (long)j * 64;
    char* Kb = (char*)lds + buf * 16384;
#pragma unroll
    for (int p = 0; p < 2; ++p) {
      const int cl = p * 256 + tid;                      // 16B chunk id 0..511
      const int krow = cl >> 3;
      const int kcb = ((cl & 7) * 16) ^ ((krow & 7) << 4);
      glds16(K + (kvoff + krow) * 64 + (kcb >> 1), Kb + p * 4096 + wave * 1024);
      const int dtv = cl >> 7, kvt = (cl >> 3) & 15, rr = (cl >> 1) & 3, hf = cl & 1;
      glds16(V + (kvoff + kvt * 4 + rr) * 64 + dtv * 16 + hf * 8,
             Kb + 8192 + p * 4096 + wave * 1024);
    }
  };

  stage(0, 0);
  asm volatile("s_waitcnt vmcnt(0)" ::: "memory");
  __builtin_amdgcn_s_barrier();

  int cur = 0;
  for (int j = 0; j <= jmax; ++j, cur ^= 1) {
    // prefetch next tile into other buffer; counted vmcnt keeps it in flight
    if (j < jmax) {
      stage(j + 1, cur ^ 1);
      asm volatile("s_waitcnt vmcnt(4)" ::: "memory");
    } else {
      asm volatile("s_waitcnt vmcnt(0)" ::: "memory");
    }
    __builtin_amdgcn_s_barrier();

    const unsigned short* Kb = lds + cur * 8192;
    const bool maskp = (j >= jdiag);

    // S^T = K * Q^T : lane holds S^T[kv=ct*16+grp*4+r][q=ln] per nt
    f32x4 sacc[4][2];
#pragma unroll
    for (int ct = 0; ct < 4; ++ct) { sacc[ct][0] = z4; sacc[ct][1] = z4; }
    __builtin_amdgcn_s_setprio(1);
#pragma unroll
    for (int ct = 0; ct < 4; ++ct) {
      const int row = ct * 16 + ln;
      const int sw = (ln & 7) << 4;
      const char* rp = (const char*)Kb + row * 128;
      const short8 kf0 = *(const short8*)(rp + ((grp * 16) ^ sw));
      const short8 kf1 = *(const short8*)(rp + ((grp * 16 + 64) ^ sw));
      sacc[ct][0] = mfma16(kf0, qf[0][0], sacc[ct][0]);
      sacc[ct][0] = mfma16(kf1, qf[0][1], sacc[ct][0]);
      sacc[ct][1] = mfma16(kf0, qf[1][0], sacc[ct][1]);
      sacc[ct][1] = mfma16(kf1, qf[1][1], sacc[ct][1]);
    }
    __builtin_amdgcn_s_setprio(0);

    // online softmax; P stays in registers (becomes PV's B operand)
    short8 pf[2][2];
#pragma unroll
    for (int nt = 0; nt < 2; ++nt) {
      if (maskp) {
        const int q = qw + nt * 16 + ln;
#pragma unroll
        for (int ct = 0; ct < 4; ++ct)
#pragma unroll
          for (int r = 0; r < 4; ++r) {
            const int kv = j * 64 + ct * 16 + grp * 4 + r;
            if (kv > q) sacc[ct][nt][r] = -INFINITY;
          }
      }
      float mx = sacc[0][nt][0];
#pragma unroll
      for (int ct = 0; ct < 4; ++ct)
#pragma unroll
        for (int r = 0; r < 4; ++r) mx = fmaxf(mx, sacc[ct][nt][r]);
      mx = fmaxf(mx, __shfl_xor(mx, 16));
      mx = fmaxf(mx, __shfl_xor(mx, 32));
      if (__any(mx > m_run[nt])) {  // defer-max: skip rescale when max didn't grow
        const float mnew = fmaxf(m_run[nt], mx);
        const float alpha = __expf(m_run[nt] - mnew);
        m_run[nt] = mnew;
        l_run[nt] *= alpha;
#pragma unroll
        for (int dt = 0; dt < 4; ++dt) accO[dt][nt] *= alpha;
      }
      float rs = 0.f;
#pragma unroll
      for (int ct = 0; ct < 4; ++ct)
#pragma unroll
        for (int r = 0; r < 4; ++r) {
          const float p = __expf(sacc[ct][nt][r] - m_run[nt]);
          rs += p;
          pf[nt][ct >> 1][(ct & 1) * 4 + r] = (short)f2b(p);
        }
      rs += __shfl_xor(rs, 16);
      rs += __shfl_xor(rs, 32);
      l_run[nt] += rs;
    }

    // O^T += V^T * P^T ; V^T A-frags via hardware transpose-read
    const unsigned vb = (unsigned)(size_t)&lds3[cur * 8192 + 4096] + (unsigned)lane * 8;
    short4v t[4][4];
#pragma unroll
    for (int dt = 0; dt < 4; ++dt) {
      const unsigned va = vb + dt * 2048;
      asm volatile("ds_read_b64_tr_b16 %0, %4 offset:0\n\t"
                   "ds_read_b64_tr_b16 %1, %4 offset:512\n\t"
                   "ds_read_b64_tr_b16 %2, %4 offset:1024\n\t"
                   "ds_read_b64_tr_b16 %3, %4 offset:1536"
                   : "=v"(t[dt][0]), "=v"(t[dt][1]), "=v"(t[dt][2]), "=v"(t[dt][3])
                   : "v"(va));
    }
    asm volatile("s_waitcnt lgkmcnt(0)" ::: "memory");
    __builtin_amdgcn_sched_barrier(0);
    __builtin_amdgcn_s_setprio(1);
#pragma unroll
    for (int dt = 0; dt < 4; ++dt) {
      const short8 vf0 = __builtin_shufflevector(t[dt][0], t[dt][1], 0, 1, 2, 3, 4, 5, 6, 7);
      const short8 vf1 = __builtin_shufflevector(t[dt][2], t[dt][3], 0, 1, 2, 3, 4, 5, 6, 7);
      accO[dt][0] = mfma16(vf0, pf[0][0], accO[dt][0]);
      accO[dt][0] = mfma16(vf1, pf[0][1], accO[dt][0]);
      accO[dt][1] = mfma16(vf0, pf[1][0], accO[dt][1]);
      accO[dt][1] = mfma16(vf1, pf[1][1], accO[dt][1]);
    }
    __builtin_amdgcn_s_setprio(0);
    asm volatile("s_waitcnt lgkmcnt(0)" ::: "memory");
    __builtin_amdgcn_s_barrier();
  }

  // epilogue: Y[b][t][h][d]; lane holds O^T[d=dt*16+grp*4+r][q=ln of tile]
  const int b = bh >> 4, h = bh & 15;
#pragma unroll
  for (int nt = 0; nt < 2; ++nt) {
    const float inv = 1.0f / l_run[nt];
    const int t_ = qw + nt * 16 + ln;
    const long base = (((long)(b * 2048 + t_)) * 16 + h) * 64;
#pragma unroll
    for (int dt = 0; dt < 4; ++dt) {
      unsigned short o[4];
#pragma unroll
      for (int r = 0; r < 4; ++r) o[r] = f2b(accO[dt][nt][r] * inv);
      *(short4v*)(Y + base + dt * 16 + grp * 4) = *(const short4v*)o;
    }
  }
}

// ---------------- output GEMM (M=8192,N=1024,K=1024), f32 out ----------------
__global__ __launch_bounds__(256) void gemm_out(
    const unsigned short* __restrict__ A, const unsigned short* __restrict__ Bt,
    float* __restrict__ C) {
  __shared__ unsigned short As[128 * 32];
  __shared__ unsigned short Bs[128 * 32];
  const int tid = threadIdx.x;
  const int wave = tid >> 6, lane = tid & 63;
  const int ln = lane & 15, grp = lane >> 4;
  const int wr = wave >> 1, wc = wave & 1;
  const int row0 = blockIdx.x * 128, col0 = blockIdx.y * 128;

  f32x4 acc[4][4];
  const f32x4 z4 = {0.f, 0.f, 0.f, 0.f};
#pragma unroll
  for (int m = 0; m < 4; ++m)
#pragma unroll
    for (int n = 0; n < 4; ++n) acc[m][n] = z4;

  for (int k0 = 0; k0 < 1024; k0 += 32) {
    __syncthreads();
#pragma unroll
    for (int p = 0; p < 2; ++p) {
      const int lin = p * 256 + tid;
      const int r = lin >> 2;
      const int c8 = (lin & 3) * 8;
      glds16(A + (long)(row0 + r) * 1024 + k0 + c8, (char*)As + p * 4096 + wave * 1024);
      glds16(Bt + (long)(col0 + r) * 1024 + k0 + c8, (char*)Bs + p * 4096 + wave * 1024);
    }
    __syncthreads();
    short8 af[4], bfv[4];
#pragma unroll
    for (int m = 0; m < 4; ++m)
      af[m] = *(const short8*)&As[(wr * 64 + m * 16 + ln) * 32 + grp * 8];
#pragma unroll
    for (int n = 0; n < 4; ++n)
      bfv[n] = *(const short8*)&Bs[(wc * 64 + n * 16 + ln) * 32 + grp * 8];
#pragma unroll
    for (int m = 0; m < 4; ++m)
#pragma unroll
      for (int n = 0; n < 4; ++n)
        acc[m][n] = mfma16(af[m], bfv[n], acc[m][n]);
  }

#pragma unroll
  for (int m = 0; m < 4; ++m)
#pragma unroll
    for (int reg = 0; reg < 4; ++reg) {
      const int row = row0 + wr * 64 + m * 16 + grp * 4 + reg;
#pragma unroll
      for (int n = 0; n < 4; ++n)
        C[(long)row * 1024 + col0 + wc * 64 + n * 16 + ln] = acc[m][n][reg];
    }
}

extern "C" void kernel_launch(void* const* d_in, const int* in_sizes, int n_in,
                              void* d_out, int out_size, void* d_ws, size_t ws_size,
                              hipStream_t stream) {
  (void)in_sizes; (void)n_in; (void)out_size; (void)ws_size;
  const float* x    = (const float*)d_in[0];
  const float* cosp = (const float*)d_in[1];
  const float* sinp = (const float*)d_in[2];
  const float* Wq   = (const float*)d_in[3];
  const float* Wk   = (const float*)d_in[4];
  const float* Wv   = (const float*)d_in[5];
  const float* Wo   = (const float*)d_in[6];
  float* out = (float*)d_out;

  unsigned short* xb  = (unsigned short*)d_ws;
  unsigned short* Wt  = xb  + (size_t)8192 * 1024;
  unsigned short* Wot = Wt  + (size_t)3 * 1024 * 1024;
  unsigned short* Qr  = Wot + (size_t)1024 * 1024;
  unsigned short* Kr  = Qr  + (size_t)8192 * 1024;
  unsigned short* Vr  = Kr  + (size_t)8192 * 1024;
  unsigned short* Yb  = xb;  // xb dead after gemm_qkv

  cast_x_kernel<<<4096, 256, 0, stream>>>(x, xb);
  transpose_cast_w<<<dim3(32, 32, 4), dim3(32, 8), 0, stream>>>(Wq, Wk, Wv, Wo, Wt, Wot);
  gemm_qkv<<<dim3(64, 24), 256, 0, stream>>>(xb, Wt, Qr, Kr, Vr, cosp, sinp);
  attn_kernel<<<1024, 256, 0, stream>>>(Qr, Kr, Vr, Yb);
  gemm_out<<<dim3(64, 8), 256, 0, stream>>>(Yb, Wot, out);
}

// Round 4
// 205.881 us; speedup vs baseline: 1.8941x; 1.1551x over previous
//
#include <hip/hip_runtime.h>

// B=4 T=2048 C=1024 H=16 D=64  N=B*T=8192

typedef __attribute__((ext_vector_type(8))) short short8;
typedef __attribute__((ext_vector_type(4))) short short4v;
typedef __attribute__((ext_vector_type(4))) float f32x4;

__device__ __forceinline__ unsigned short f2b(float f) {
  union { float f; unsigned int i; } x; x.f = f;
  return (unsigned short)((x.i + 0x7FFFu + ((x.i >> 16) & 1u)) >> 16);
}

// hardware RNE f32->bf16
__device__ __forceinline__ unsigned short b16(float f) {
  return __builtin_bit_cast(unsigned short, (__bf16)f);
}

__device__ __forceinline__ void glds16(const void* g, void* l) {
  __builtin_amdgcn_global_load_lds((const __attribute__((address_space(1))) unsigned int*)g,
                                   (__attribute__((address_space(3))) unsigned int*)l,
                                   16, 0, 0);
}

__device__ __forceinline__ f32x4 mfma16(short8 a, short8 b, f32x4 c) {
  return __builtin_amdgcn_mfma_f32_16x16x32_bf16(a, b, c, 0, 0, 0);
}

// ---------------- cast x: f32 -> bf16, 8 elems/thread ----------------
__global__ __launch_bounds__(256) void cast_x_kernel(const float* __restrict__ x,
                                                     unsigned short* __restrict__ xb) {
  const long i = ((long)blockIdx.x * 256 + threadIdx.x) * 8;
  const float4 a = *(const float4*)(x + i);
  const float4 b = *(const float4*)(x + i + 4);
  unsigned short o[8] = {f2b(a.x), f2b(a.y), f2b(a.z), f2b(a.w),
                         f2b(b.x), f2b(b.y), f2b(b.z), f2b(b.w)};
  *(short8*)(xb + i) = *(const short8*)o;
}

// ---------------- transpose+cast weights: dst[n][k] = W[k][n] ----------------
__global__ __launch_bounds__(256) void transpose_cast_w(
    const float* __restrict__ W0, const float* __restrict__ W1,
    const float* __restrict__ W2, const float* __restrict__ W3,
    unsigned short* __restrict__ Wt, unsigned short* __restrict__ Wot) {
  const int z = blockIdx.z;
  const float* __restrict__ W = (z == 0) ? W0 : (z == 1) ? W1 : (z == 2) ? W2 : W3;
  unsigned short* __restrict__ dst = (z < 3) ? (Wt + (size_t)z * 1024 * 1024) : Wot;
  __shared__ float tile[32][33];
  const int tx = threadIdx.x, ty = threadIdx.y;
  const int bx = blockIdx.x * 32, by = blockIdx.y * 32;
#pragma unroll
  for (int i = 0; i < 4; ++i)
    tile[ty + 8 * i][tx] = W[(size_t)(by + ty + 8 * i) * 1024 + bx + tx];
  __syncthreads();
#pragma unroll
  for (int i = 0; i < 4; ++i)
    dst[(size_t)(bx + ty + 8 * i) * 1024 + by + tx] = f2b(tile[tx][ty + 8 * i]);
}

// ---------------- QKV GEMM (M=8192,N=3072,K=1024) + fused RoPE/RMS epilogue ----------------
// Q pre-scaled by (1/sqrt(D)) * log2(e) so attention scores are in log2 domain.
__global__ __launch_bounds__(256) void gemm_qkv(
    const unsigned short* __restrict__ A, const unsigned short* __restrict__ Bt,
    unsigned short* __restrict__ Qr, unsigned short* __restrict__ Kr,
    unsigned short* __restrict__ Vr,
    const float* __restrict__ cosp, const float* __restrict__ sinp) {
  __shared__ unsigned short As[128 * 32];
  __shared__ unsigned short Bs[128 * 32];
  const int tid = threadIdx.x;
  const int wave = tid >> 6, lane = tid & 63;
  const int ln = lane & 15, grp = lane >> 4;
  const int wr = wave >> 1, wc = wave & 1;
  const int row0 = blockIdx.x * 128, col0 = blockIdx.y * 128;

  f32x4 acc[4][4];
  const f32x4 z4 = {0.f, 0.f, 0.f, 0.f};
#pragma unroll
  for (int m = 0; m < 4; ++m)
#pragma unroll
    for (int n = 0; n < 4; ++n) acc[m][n] = z4;

  for (int k0 = 0; k0 < 1024; k0 += 32) {
    __syncthreads();
#pragma unroll
    for (int p = 0; p < 2; ++p) {
      const int lin = p * 256 + tid;
      const int r = lin >> 2;
      const int c8 = (lin & 3) * 8;
      glds16(A + (long)(row0 + r) * 1024 + k0 + c8, (char*)As + p * 4096 + wave * 1024);
      glds16(Bt + (long)(col0 + r) * 1024 + k0 + c8, (char*)Bs + p * 4096 + wave * 1024);
    }
    __syncthreads();
    short8 af[4], bfv[4];
#pragma unroll
    for (int m = 0; m < 4; ++m)
      af[m] = *(const short8*)&As[(wr * 64 + m * 16 + ln) * 32 + grp * 8];
#pragma unroll
    for (int n = 0; n < 4; ++n)
      bfv[n] = *(const short8*)&Bs[(wc * 64 + n * 16 + ln) * 32 + grp * 8];
#pragma unroll
    for (int m = 0; m < 4; ++m)
#pragma unroll
      for (int n = 0; n < 4; ++n)
        acc[m][n] = mfma16(af[m], bfv[n], acc[m][n]);
  }

  const int colbase = col0 + wc * 64;
  const int z = colbase >> 10;
  const int h = (colbase & 1023) >> 6;
  unsigned short* __restrict__ dst = (z == 0) ? Qr : (z == 1) ? Kr : Vr;

  if (z < 2) {  // RoPE + RMS-norm for Q,K (Q pre-scaled: 0.125 * log2(e))
    const float qs = (z == 0) ? 0.125f * 1.44269504f : 1.0f;
#pragma unroll
    for (int m = 0; m < 4; ++m) {
#pragma unroll
      for (int reg = 0; reg < 4; ++reg) {
        const int row = row0 + wr * 64 + m * 16 + grp * 4 + reg;
        const int t = row & 2047, b = row >> 11;
        const float u0 = acc[m][0][reg], u1 = acc[m][1][reg];
        const float u2 = acc[m][2][reg], u3 = acc[m][3][reg];
        const float c0 = cosp[t * 32 + ln],      s0 = sinp[t * 32 + ln];
        const float c1 = cosp[t * 32 + 16 + ln], s1 = sinp[t * 32 + 16 + ln];
        const float r0 =  u0 * c0 + u2 * s0;
        const float r1 =  u1 * c1 + u3 * s1;
        const float r2 = -u0 * s0 + u2 * c0;
        const float r3 = -u1 * s1 + u3 * c1;
        float ss = r0 * r0 + r1 * r1 + r2 * r2 + r3 * r3;
        ss += __shfl_xor(ss, 1); ss += __shfl_xor(ss, 2);
        ss += __shfl_xor(ss, 4); ss += __shfl_xor(ss, 8);
        const float inv = rsqrtf(ss * (1.0f / 64.0f) + 1.1920929e-07f) * qs;
        const long base = (((long)(b * 16 + h)) * 2048 + t) * 64;
        dst[base + ln]      = f2b(r0 * inv);
        dst[base + 16 + ln] = f2b(r1 * inv);
        dst[base + 32 + ln] = f2b(r2 * inv);
        dst[base + 48 + ln] = f2b(r3 * inv);
      }
    }
  } else {  // plain relayout for V
#pragma unroll
    for (int m = 0; m < 4; ++m) {
#pragma unroll
      for (int reg = 0; reg < 4; ++reg) {
        const int row = row0 + wr * 64 + m * 16 + grp * 4 + reg;
        const int t = row & 2047, b = row >> 11;
        const long base = (((long)(b * 16 + h)) * 2048 + t) * 64;
#pragma unroll
        for (int n = 0; n < 4; ++n)
          dst[base + n * 16 + ln] = f2b(acc[m][n][reg]);
      }
    }
  }
}

// ---------------- causal flash attention (swapped-operand, tr-read V) ----------------
// Q/K/V: bf16 [B*H][T][64]; Y: bf16 [B][T][H][64]
// 512 blocks: each handles q-tiles {pr, 15-pr} of one bh => uniform 34 kv-iters/block.
__global__ __launch_bounds__(256) void attn_kernel(
    const unsigned short* __restrict__ Q, const unsigned short* __restrict__ K,
    const unsigned short* __restrict__ V, unsigned short* __restrict__ Y) {
  __shared__ unsigned short lds[2 * 8192];
  const int tid = threadIdx.x;
  const int wave = tid >> 6, lane = tid & 63;
  const int ln = lane & 15, grp = lane >> 4;

  const int linb = blockIdx.x;          // 512 blocks
  const int xcd = linb & 7, slot = linb >> 3;
  const int bh = xcd * 8 + (slot >> 3); // 8 heads per XCD => K/V L2-resident
  const int pr = slot & 7;

  const long bhT = (long)bh * 2048;
  const int b = bh >> 4, h = bh & 15;
  auto* lds3 = (__attribute__((address_space(3))) unsigned short*)lds;

  auto stage = [&](int j, int buf) {
    const long kvoff = bhT + (long)j * 64;
    char* Kb = (char*)lds + buf * 16384;
#pragma unroll
    for (int p = 0; p < 2; ++p) {
      const int cl = p * 256 + tid;                      // 16B chunk id 0..511
      const int krow = cl >> 3;
      const int kcb = ((cl & 7) * 16) ^ ((krow & 7) << 4);
      glds16(K + (kvoff + krow) * 64 + (kcb >> 1), Kb + p * 4096 + wave * 1024);
      const int dtv = cl >> 7, kvt = (cl >> 3) & 15, rr = (cl >> 1) & 3, hf = cl & 1;
      glds16(V + (kvoff + kvt * 4 + rr) * 64 + dtv * 16 + hf * 8,
             Kb + 8192 + p * 4096 + wave * 1024);
    }
  };

  const f32x4 z4 = {0.f, 0.f, 0.f, 0.f};

  for (int half = 0; half < 2; ++half) {
    const int bx = (half == 0) ? pr : 15 - pr;
    const int q0 = bx * 128;
    const int qw = q0 + wave * 32;
    const int jmax = 2 * bx + 1;
    const int jdiag = 2 * bx;

    short8 qf[2][2];
#pragma unroll
    for (int nt = 0; nt < 2; ++nt)
#pragma unroll
      for (int c = 0; c < 2; ++c)
        qf[nt][c] = *(const short8*)(Q + (bhT + qw + nt * 16 + ln) * 64 + c * 32 + grp * 8);

    f32x4 accO[4][2];
#pragma unroll
    for (int dt = 0; dt < 4; ++dt) { accO[dt][0] = z4; accO[dt][1] = z4; }
    float m_run[2] = {-INFINITY, -INFINITY};
    float l_run[2] = {0.f, 0.f};

    stage(0, 0);
    asm volatile("s_waitcnt vmcnt(0)" ::: "memory");
    __builtin_amdgcn_s_barrier();

    int cur = 0;
    for (int j = 0; j <= jmax; ++j, cur ^= 1) {
      if (j < jmax) {
        stage(j + 1, cur ^ 1);
        asm volatile("s_waitcnt vmcnt(4)" ::: "memory");
      } else {
        asm volatile("s_waitcnt vmcnt(0)" ::: "memory");
      }
      __builtin_amdgcn_s_barrier();

      const unsigned short* Kb = lds + cur * 8192;
      const bool maskp = (j >= jdiag);

      // S^T = K * Q^T : lane holds S^T[kv=ct*16+grp*4+r][q=ln] per nt (log2 domain)
      f32x4 sacc[4][2];
#pragma unroll
      for (int ct = 0; ct < 4; ++ct) { sacc[ct][0] = z4; sacc[ct][1] = z4; }
      __builtin_amdgcn_s_setprio(1);
#pragma unroll
      for (int ct = 0; ct < 4; ++ct) {
        const int row = ct * 16 + ln;
        const int sw = (ln & 7) << 4;
        const char* rp = (const char*)Kb + row * 128;
        const short8 kf0 = *(const short8*)(rp + ((grp * 16) ^ sw));
        const short8 kf1 = *(const short8*)(rp + ((grp * 16 + 64) ^ sw));
        sacc[ct][0] = mfma16(kf0, qf[0][0], sacc[ct][0]);
        sacc[ct][0] = mfma16(kf1, qf[0][1], sacc[ct][0]);
        sacc[ct][1] = mfma16(kf0, qf[1][0], sacc[ct][1]);
        sacc[ct][1] = mfma16(kf1, qf[1][1], sacc[ct][1]);
      }
      __builtin_amdgcn_s_setprio(0);

      // online softmax in log2 domain; P stays in registers (PV's B operand)
      short8 pf[2][2];
#pragma unroll
      for (int nt = 0; nt < 2; ++nt) {
        if (maskp) {
          const int q = qw + nt * 16 + ln;
#pragma unroll
          for (int ct = 0; ct < 4; ++ct)
#pragma unroll
            for (int r = 0; r < 4; ++r) {
              const int kv = j * 64 + ct * 16 + grp * 4 + r;
              if (kv > q) sacc[ct][nt][r] = -INFINITY;
            }
        }
        float mx = sacc[0][nt][0];
#pragma unroll
        for (int ct = 0; ct < 4; ++ct)
#pragma unroll
          for (int r = 0; r < 4; ++r) mx = fmaxf(mx, sacc[ct][nt][r]);
        mx = fmaxf(mx, __shfl_xor(mx, 16));
        mx = fmaxf(mx, __shfl_xor(mx, 32));
        // defer-max (T13): only rescale when max grew by more than THR=8
        if (!__all(mx - m_run[nt] <= 8.f)) {
          const float mnew = fmaxf(m_run[nt], mx);
          const float alpha = exp2f(m_run[nt] - mnew);
          m_run[nt] = mnew;
          l_run[nt] *= alpha;
#pragma unroll
          for (int dt = 0; dt < 4; ++dt) accO[dt][nt] *= alpha;
        }
        float rs = 0.f;
#pragma unroll
        for (int ct = 0; ct < 4; ++ct)
#pragma unroll
          for (int r = 0; r < 4; ++r) {
            const float p = exp2f(sacc[ct][nt][r] - m_run[nt]);
            rs += p;
            pf[nt][ct >> 1][(ct & 1) * 4 + r] = (short)b16(p);
          }
        rs += __shfl_xor(rs, 16);
        rs += __shfl_xor(rs, 32);
        l_run[nt] += rs;
      }

      // O^T += V^T * P^T ; V^T A-frags via hardware transpose-read.
      // "=&v" early-clobber is REQUIRED: outputs are written asynchronously
      // (lgkmcnt) and must never share a register with the address input %4,
      // else a mid-sequence data return corrupts the address (timing race).
      const unsigned vb = (unsigned)(size_t)&lds3[cur * 8192 + 4096] + (unsigned)lane * 8;
      short4v t[4][4];
#pragma unroll
      for (int dt = 0; dt < 4; ++dt) {
        const unsigned va = vb + dt * 2048;
        asm volatile("ds_read_b64_tr_b16 %0, %4 offset:0\n\t"
                     "ds_read_b64_tr_b16 %1, %4 offset:512\n\t"
                     "ds_read_b64_tr_b16 %2, %4 offset:1024\n\t"
                     "ds_read_b64_tr_b16 %3, %4 offset:1536"
                     : "=&v"(t[dt][0]), "=&v"(t[dt][1]), "=&v"(t[dt][2]), "=&v"(t[dt][3])
                     : "v"(va));
      }
      asm volatile("s_waitcnt lgkmcnt(0)" ::: "memory");
      __builtin_amdgcn_sched_barrier(0);
      __builtin_amdgcn_s_setprio(1);
#pragma unroll
      for (int dt = 0; dt < 4; ++dt) {
        const short8 vf0 = __builtin_shufflevector(t[dt][0], t[dt][1], 0, 1, 2, 3, 4, 5, 6, 7);
        const short8 vf1 = __builtin_shufflevector(t[dt][2], t[dt][3], 0, 1, 2, 3, 4, 5, 6, 7);
        accO[dt][0] = mfma16(vf0, pf[0][0], accO[dt][0]);
        accO[dt][0] = mfma16(vf1, pf[0][1], accO[dt][0]);
        accO[dt][1] = mfma16(vf0, pf[1][0], accO[dt][1]);
        accO[dt][1] = mfma16(vf1, pf[1][1], accO[dt][1]);
      }
      __builtin_amdgcn_s_setprio(0);
      asm volatile("s_waitcnt lgkmcnt(0)" ::: "memory");
      __builtin_amdgcn_s_barrier();
    }

    // epilogue: Y[b][t][h][d]; lane holds O^T[d=dt*16+grp*4+r][q=ln of tile]
#pragma unroll
    for (int nt = 0; nt < 2; ++nt) {
      const float inv = 1.0f / l_run[nt];
      const int t_ = qw + nt * 16 + ln;
      const long base = (((long)(b * 2048 + t_)) * 16 + h) * 64;
#pragma unroll
      for (int dt = 0; dt < 4; ++dt) {
        unsigned short o[4];
#pragma unroll
        for (int r = 0; r < 4; ++r) o[r] = b16(accO[dt][nt][r] * inv);
        *(short4v*)(Y + base + dt * 16 + grp * 4) = *(const short4v*)o;
      }
    }
  }
}

// ---------------- output GEMM (M=8192,N=1024,K=1024), f32 out ----------------
__global__ __launch_bounds__(256) void gemm_out(
    const unsigned short* __restrict__ A, const unsigned short* __restrict__ Bt,
    float* __restrict__ C) {
  __shared__ unsigned short As[128 * 32];
  __shared__ unsigned short Bs[128 * 32];
  const int tid = threadIdx.x;
  const int wave = tid >> 6, lane = tid & 63;
  const int ln = lane & 15, grp = lane >> 4;
  const int wr = wave >> 1, wc = wave & 1;
  const int row0 = blockIdx.x * 128, col0 = blockIdx.y * 128;

  f32x4 acc[4][4];
  const f32x4 z4 = {0.f, 0.f, 0.f, 0.f};
#pragma unroll
  for (int m = 0; m < 4; ++m)
#pragma unroll
    for (int n = 0; n < 4; ++n) acc[m][n] = z4;

  for (int k0 = 0; k0 < 1024; k0 += 32) {
    __syncthreads();
#pragma unroll
    for (int p = 0; p < 2; ++p) {
      const int lin = p * 256 + tid;
      const int r = lin >> 2;
      const int c8 = (lin & 3) * 8;
      glds16(A + (long)(row0 + r) * 1024 + k0 + c8, (char*)As + p * 4096 + wave * 1024);
      glds16(Bt + (long)(col0 + r) * 1024 + k0 + c8, (char*)Bs + p * 4096 + wave * 1024);
    }
    __syncthreads();
    short8 af[4], bfv[4];
#pragma unroll
    for (int m = 0; m < 4; ++m)
      af[m] = *(const short8*)&As[(wr * 64 + m * 16 + ln) * 32 + grp * 8];
#pragma unroll
    for (int n = 0; n < 4; ++n)
      bfv[n] = *(const short8*)&Bs[(wc * 64 + n * 16 + ln) * 32 + grp * 8];
#pragma unroll
    for (int m = 0; m < 4; ++m)
#pragma unroll
      for (int n = 0; n < 4; ++n)
        acc[m][n] = mfma16(af[m], bfv[n], acc[m][n]);
  }

#pragma unroll
  for (int m = 0; m < 4; ++m)
#pragma unroll
    for (int reg = 0; reg < 4; ++reg) {
      const int row = row0 + wr * 64 + m * 16 + grp * 4 + reg;
#pragma unroll
      for (int n = 0; n < 4; ++n)
        C[(long)row * 1024 + col0 + wc * 64 + n * 16 + ln] = acc[m][n][reg];
    }
}

extern "C" void kernel_launch(void* const* d_in, const int* in_sizes, int n_in,
                              void* d_out, int out_size, void* d_ws, size_t ws_size,
                              hipStream_t stream) {
  (void)in_sizes; (void)n_in; (void)out_size; (void)ws_size;
  const float* x    = (const float*)d_in[0];
  const float* cosp = (const float*)d_in[1];
  const float* sinp = (const float*)d_in[2];
  const float* Wq   = (const float*)d_in[3];
  const float* Wk   = (const float*)d_in[4];
  const float* Wv   = (const float*)d_in[5];
  const float* Wo   = (const float*)d_in[6];
  float* out = (float*)d_out;

  unsigned short* xb  = (unsigned short*)d_ws;
  unsigned short* Wt  = xb  + (size_t)8192 * 1024;
  unsigned short* Wot = Wt  + (size_t)3 * 1024 * 1024;
  unsigned short* Qr  = Wot + (size_t)1024 * 1024;
  unsigned short* Kr  = Qr  + (size_t)8192 * 1024;
  unsigned short* Vr  = Kr  + (size_t)8192 * 1024;
  unsigned short* Yb  = xb;  // xb dead after gemm_qkv

  cast_x_kernel<<<4096, 256, 0, stream>>>(x, xb);
  transpose_cast_w<<<dim3(32, 32, 4), dim3(32, 8), 0, stream>>>(Wq, Wk, Wv, Wo, Wt, Wot);
  gemm_qkv<<<dim3(64, 24), 256, 0, stream>>>(xb, Wt, Qr, Kr, Vr, cosp, sinp);
  attn_kernel<<<512, 256, 0, stream>>>(Qr, Kr, Vr, Yb);
  gemm_out<<<dim3(64, 8), 256, 0, stream>>>(Yb, Wot, out);
}